// Round 1
// 140.415 us; speedup vs baseline: 1.0981x; 1.0981x over previous
//
#include <hip/hip_runtime.h>

typedef _Float16 half8 __attribute__((ext_vector_type(8)));
typedef _Float16 half4v __attribute__((ext_vector_type(4)));
typedef float   float4v __attribute__((ext_vector_type(4)));

#define S_LEN 4096
#define NBATCH 4
#define NCHUNK 4          // K-split factor: each chunk covers S/NCHUNK keys
// ws layout in halves:
//   W16  @ 0        : 256*128      = 32768
//   Qh   @ 32768    : 16384*64     = 1048576   (token-major [B*S][64])
//   Kh   @ 1081344  : 16384*64     = 1048576
//   Vt   @ 2129920  : 4*128*4096   = 2097152   (per-batch transposed [128][S])
//   L    @ 4227072  : 16384 floats (row sum-of-exp accumulators)
#define WS_W16 0
#define WS_QH  32768
#define WS_KH  1081344
#define WS_VT  2129920
#define WS_L   4227072

// ---------------- kernel 0: zero accumulators + convert weights (fused) ------
// grid 2048 x 256. i covers 524288 float4 of out; first 4096 also zero lbuf;
// first 32768 threads also convert one weight element fp32->fp16.
__global__ __launch_bounds__(256) void init_kernel(const float* __restrict__ Wq,
                                                   const float* __restrict__ Wk,
                                                   const float* __restrict__ Wv,
                                                   _Float16* __restrict__ w16,
                                                   float4v* __restrict__ out4,
                                                   float4v* __restrict__ l4) {
    int i = blockIdx.x * 256 + threadIdx.x;   // 0..524287
    out4[i] = (float4v){0.f, 0.f, 0.f, 0.f};
    if (i < 4096) l4[i] = (float4v){0.f, 0.f, 0.f, 0.f};
    if (i < 32768) {
        int row = i >> 7, col = i & 127;
        float v;
        if (row < 64)       v = Wq[row * 128 + col];
        else if (row < 128) v = Wk[(row - 64) * 128 + col];
        else                v = Wv[(row - 128) * 128 + col];
        w16[i] = (_Float16)v;
    }
}

// ---------------- kernel 1: QKV projection via MFMA ---------------------------
// y[token][oc] = sum_d x[token][d] * W[oc][d], oc in [0,256): 0-63 Q, 64-127 K, 128-255 V
// grid 1024 blocks x 256 thr; block owns 16 tokens; wave w owns oc [w*64, +64):
//   wave 0 -> Q, wave 1 -> K, waves 2,3 -> V. 4 blocks/CU = 16 waves/CU.
__global__ __launch_bounds__(256) void qkv_proj_kernel(const float* __restrict__ x,
                                                       const _Float16* __restrict__ w16,
                                                       _Float16* __restrict__ Qh,
                                                       _Float16* __restrict__ Kh,
                                                       _Float16* __restrict__ Vt) {
    __shared__ _Float16 xs[16 * 136];   // 16 rows, stride 136 halves (pad 128->136)
    const int t = threadIdx.x;
    const int blk = blockIdx.x;
    const float* xb = x + (size_t)blk * 16 * 128;

    for (int it = 0; it < 2; ++it) {
        int i = t + it * 256;           // 0..511 float4
        int row = i >> 5, c4 = i & 31;
        float4v f = ((const float4v*)xb)[i];
        half4v h;
        h[0] = (_Float16)f[0]; h[1] = (_Float16)f[1];
        h[2] = (_Float16)f[2]; h[3] = (_Float16)f[3];
        *(half4v*)&xs[row * 136 + c4 * 4] = h;
    }
    __syncthreads();

    const int w = t >> 6, lane = t & 63, quad = lane >> 4, n16 = lane & 15;

    half8 a[4];
    for (int c = 0; c < 4; ++c)
        a[c] = *(const half8*)&xs[n16 * 136 + c * 32 + quad * 8];

    float4v acc[4];
    for (int nb = 0; nb < 4; ++nb) acc[nb] = (float4v){0.f, 0.f, 0.f, 0.f};

    for (int c = 0; c < 4; ++c) {
        for (int nb = 0; nb < 4; ++nb) {
            int oc = w * 64 + nb * 16 + n16;
            half8 bfr = *(const half8*)&w16[(size_t)oc * 128 + c * 32 + quad * 8];
            acc[nb] = __builtin_amdgcn_mfma_f32_16x16x32_f16(a[c], bfr, acc[nb], 0, 0, 0);
        }
    }

    const int token0 = blk * 16 + quad * 4;
    if (w == 0) {
        for (int nb = 0; nb < 4; ++nb)
            for (int r = 0; r < 4; ++r)
                Qh[(size_t)(token0 + r) * 64 + nb * 16 + n16] = (_Float16)acc[nb][r];
    } else if (w == 1) {
        for (int nb = 0; nb < 4; ++nb)
            for (int r = 0; r < 4; ++r)
                Kh[(size_t)(token0 + r) * 64 + nb * 16 + n16] = (_Float16)acc[nb][r];
    } else {
        int bb = token0 >> 12, s0 = token0 & 4095;
        for (int nb = 0; nb < 4; ++nb) {
            int vc = (w - 2) * 64 + nb * 16 + n16;
            half4v h;
            h[0] = (_Float16)acc[nb][0]; h[1] = (_Float16)acc[nb][1];
            h[2] = (_Float16)acc[nb][2]; h[3] = (_Float16)acc[nb][3];
            *(half4v*)&Vt[((size_t)bb * 128 + vc) * S_LEN + s0] = h;
        }
    }
}

// ---------------- kernel 2: flash attention, K-split x4 -----------------------
// grid (S/64, NCHUNK, B), 256 threads. Wave w owns q rows [qt*64 + w*16, +16).
// Shifted-exp softmax: p = exp(s*0.125 - 4) -- constant shift makes partial
// (O, l) EXACTLY additive across key chunks -> accumulate via HW fp32 atomics.
//
// This round: (a) T14 register prefetch of next K/V tile (latency hidden under
// QK+PV), (b) 2 barriers/iter (Ps is per-wave: in-wave lgkmcnt orders its
// write->read, barrier 3 removed), (c) XOR-swizzled Ps stores (conflict-free:
// physical col group = nb ^ quad; quads land on disjoint 8-bank groups),
// (d) setprio(1) around MFMA clusters.
#define KT 64
__global__ __launch_bounds__(256) void flash_kernel(const _Float16* __restrict__ Qh,
                                                    const _Float16* __restrict__ Kh,
                                                    const _Float16* __restrict__ Vt,
                                                    float* __restrict__ out,
                                                    float* __restrict__ lbuf) {
    __shared__ _Float16 Ks[KT * 72];        // K tile [64][64], padded stride 72
    __shared__ _Float16 Vs[128 * 72];       // V^T tile [128][64], padded stride 72
    __shared__ _Float16 Ps[4][16 * 72];     // per-wave P [16][64], col-group swizzled

    const int t = threadIdx.x;
    const int qt = blockIdx.x, chunk = blockIdx.y, b = blockIdx.z;
    const int w = t >> 6, lane = t & 63, quad = lane >> 4, n16 = lane & 15;

    const size_t qrow = (size_t)b * S_LEN + qt * 64 + w * 16 + n16;
    half8 aQ0 = *(const half8*)&Qh[qrow * 64 + quad * 8];
    half8 aQ1 = *(const half8*)&Qh[qrow * 64 + 32 + quad * 8];

    float4v O[8];
    for (int vb = 0; vb < 8; ++vb) O[vb] = (float4v){0.f, 0.f, 0.f, 0.f};
    float lsum[4] = {0.f, 0.f, 0.f, 0.f};

    const _Float16* Kb = Kh + (size_t)b * S_LEN * 64;
    const _Float16* Vb = Vt + (size_t)b * 128 * S_LEN;

    const int kt0 = chunk * (S_LEN / KT / NCHUNK);
    const int kt1 = kt0 + (S_LEN / KT / NCHUNK);

    // LDS store coords (i = t and i = t+256; note (t+256)&7 == t&7)
    const int kr0 = t >> 3, kc0 = t & 7;
    const int kr1 = (t + 256) >> 3;

    // -------- prologue: load tile kt0 into registers --------
    half8 kreg0, kreg1, vreg[4];
    {
        const half8* srcK = (const half8*)(Kb + (size_t)kt0 * KT * 64);
        kreg0 = srcK[t];
        kreg1 = srcK[t + 256];
        for (int it = 0; it < 4; ++it) {
            int i = t + it * 256, row = i >> 3, c8 = i & 7;
            vreg[it] = *(const half8*)&Vb[(size_t)row * S_LEN + kt0 * KT + c8 * 8];
        }
    }

    for (int kt = kt0; kt < kt1; ++kt) {
        __syncthreads();                          // all waves done reading prev tile
        // staged regs -> LDS
        *(half8*)&Ks[kr0 * 72 + kc0 * 8] = kreg0;
        *(half8*)&Ks[kr1 * 72 + kc0 * 8] = kreg1;
        for (int it = 0; it < 4; ++it) {
            int i = t + it * 256, row = i >> 3, c8 = i & 7;
            *(half8*)&Vs[row * 72 + c8 * 8] = vreg[it];
        }
        __syncthreads();                          // tile visible to all waves

        // -------- issue next-tile loads now; latency hides under QK+PV --------
        if (kt + 1 < kt1) {
            const half8* srcK = (const half8*)(Kb + (size_t)(kt + 1) * KT * 64);
            kreg0 = srcK[t];
            kreg1 = srcK[t + 256];
            for (int it = 0; it < 4; ++it) {
                int i = t + it * 256, row = i >> 3, c8 = i & 7;
                vreg[it] = *(const half8*)&Vb[(size_t)row * S_LEN + (kt + 1) * KT + c8 * 8];
            }
        }

        __builtin_amdgcn_s_setprio(1);
        for (int nb = 0; nb < 4; ++nb) {
            float4v sc = (float4v){0.f, 0.f, 0.f, 0.f};
            half8 bK0 = *(const half8*)&Ks[(nb * 16 + n16) * 72 + quad * 8];
            half8 bK1 = *(const half8*)&Ks[(nb * 16 + n16) * 72 + 32 + quad * 8];
            sc = __builtin_amdgcn_mfma_f32_16x16x32_f16(aQ0, bK0, sc, 0, 0, 0);
            sc = __builtin_amdgcn_mfma_f32_16x16x32_f16(aQ1, bK1, sc, 0, 0, 0);
            for (int r = 0; r < 4; ++r) {
                // exp(s*0.125 - 4) == exp2(fma(s, 0.125*log2e, -4*log2e)); 1 fma + 1 v_exp
                float p = __builtin_amdgcn_exp2f(__builtin_fmaf(sc[r], 0.18033688f, -5.7707802f));
                lsum[r] += p;
                // swizzled store: physical col group = nb ^ (row>>2) = nb ^ quad
                Ps[w][(quad * 4 + r) * 72 + ((nb ^ quad) << 4) + n16] = (_Float16)p;
            }
        }
        __builtin_amdgcn_s_setprio(0);

        // per-wave Ps: in-wave DS ordering suffices, no barrier needed.
        // read row n16, logical cols [quad*8,+8) and [32+quad*8,+8);
        // group g ^ (n16>>2) is the swizzle inverse.
        half8 aP0 = *(const half8*)&Ps[w][n16 * 72 +
                        ((((quad >> 1) ^ (n16 >> 2)) << 4) | ((quad & 1) * 8))];
        half8 aP1 = *(const half8*)&Ps[w][n16 * 72 +
                        (((((quad >> 1) | 2) ^ (n16 >> 2)) << 4) | ((quad & 1) * 8))];

        __builtin_amdgcn_s_setprio(1);
        for (int vb = 0; vb < 8; ++vb) {
            half8 bV0 = *(const half8*)&Vs[(vb * 16 + n16) * 72 + quad * 8];
            half8 bV1 = *(const half8*)&Vs[(vb * 16 + n16) * 72 + 32 + quad * 8];
            O[vb] = __builtin_amdgcn_mfma_f32_16x16x32_f16(aP0, bV0, O[vb], 0, 0, 0);
            O[vb] = __builtin_amdgcn_mfma_f32_16x16x32_f16(aP1, bV1, O[vb], 0, 0, 0);
        }
        __builtin_amdgcn_s_setprio(0);
    }

    // reduce row sums across the 16 lanes of each quad
    for (int m = 1; m < 16; m <<= 1)
        for (int r = 0; r < 4; ++r)
            lsum[r] += __shfl_xor(lsum[r], m, 16);

    const int row0 = qt * 64 + w * 16 + quad * 4;            // within batch
    if (n16 == 0)
        for (int r = 0; r < 4; ++r)
            unsafeAtomicAdd(&lbuf[b * S_LEN + row0 + r], lsum[r]);

    float* ob = out + ((size_t)b * S_LEN + row0) * 128;
    for (int vb = 0; vb < 8; ++vb)
        for (int r = 0; r < 4; ++r)
            unsafeAtomicAdd(&ob[(size_t)r * 128 + vb * 16 + n16], O[vb][r]);
}

// ---------------- kernel 3: normalize out by row sums -------------------------
__global__ __launch_bounds__(256) void norm_kernel(float4v* __restrict__ out4,
                                                   const float* __restrict__ lbuf) {
    int i = blockIdx.x * 256 + threadIdx.x;   // 0..524287 (32 float4 per row)
    float inv = 1.0f / lbuf[i >> 5];
    float4v v = out4[i];
    v[0] *= inv; v[1] *= inv; v[2] *= inv; v[3] *= inv;
    out4[i] = v;
}

// ---------------- launch ------------------------------------------------------
extern "C" void kernel_launch(void* const* d_in, const int* in_sizes, int n_in,
                              void* d_out, int out_size, void* d_ws, size_t ws_size,
                              hipStream_t stream) {
    const float* x  = (const float*)d_in[0];
    const float* Wq = (const float*)d_in[1];
    const float* Wk = (const float*)d_in[2];
    const float* Wv = (const float*)d_in[3];
    float* out = (float*)d_out;

    _Float16* ws = (_Float16*)d_ws;
    _Float16* w16 = ws + WS_W16;
    _Float16* Qh  = ws + WS_QH;
    _Float16* Kh  = ws + WS_KH;
    _Float16* Vt  = ws + WS_VT;
    float*    lbuf = (float*)(ws + WS_L);

    init_kernel<<<2048, 256, 0, stream>>>(Wq, Wk, Wv, w16, (float4v*)out, (float4v*)lbuf);
    qkv_proj_kernel<<<NBATCH * S_LEN / 16, 256, 0, stream>>>(x, w16, Qh, Kh, Vt);
    flash_kernel<<<dim3(S_LEN / 64, NCHUNK, NBATCH), 256, 0, stream>>>(Qh, Kh, Vt, out, lbuf);
    norm_kernel<<<2048, 256, 0, stream>>>((float4v*)out, lbuf);
}

// Round 2
// 136.331 us; speedup vs baseline: 1.1310x; 1.0300x over previous
//
#include <hip/hip_runtime.h>

typedef _Float16 half8 __attribute__((ext_vector_type(8)));
typedef _Float16 half4v __attribute__((ext_vector_type(4)));
typedef float   float4v __attribute__((ext_vector_type(4)));

#define S_LEN 4096
#define NBATCH 4
#define NCHUNK 4          // K-split factor: each chunk covers S/NCHUNK keys
// ws layout in halves:
//   W16  @ 0        : 256*128      = 32768
//   Qh   @ 32768    : 16384*64     = 1048576   (token-major [B*S][64])
//   Kh   @ 1081344  : 16384*64     = 1048576
//   Vt   @ 2129920  : 4*128*4096   = 2097152   (per-batch transposed [128][S])
//   L    @ 4227072  : 16384 floats (row sum-of-exp accumulators)
#define WS_W16 0
#define WS_QH  32768
#define WS_KH  1081344
#define WS_VT  2129920
#define WS_L   4227072

// ---------------- kernel 0: zero accumulators + convert weights (fused) ------
__global__ __launch_bounds__(256) void init_kernel(const float* __restrict__ Wq,
                                                   const float* __restrict__ Wk,
                                                   const float* __restrict__ Wv,
                                                   _Float16* __restrict__ w16,
                                                   float4v* __restrict__ out4,
                                                   float4v* __restrict__ l4) {
    int i = blockIdx.x * 256 + threadIdx.x;   // 0..524287
    out4[i] = (float4v){0.f, 0.f, 0.f, 0.f};
    if (i < 4096) l4[i] = (float4v){0.f, 0.f, 0.f, 0.f};
    if (i < 32768) {
        int row = i >> 7, col = i & 127;
        float v;
        if (row < 64)       v = Wq[row * 128 + col];
        else if (row < 128) v = Wk[(row - 64) * 128 + col];
        else                v = Wv[(row - 128) * 128 + col];
        w16[i] = (_Float16)v;
    }
}

// ---------------- kernel 1: QKV projection via MFMA ---------------------------
// grid 1024 blocks x 256 thr; block owns 16 tokens; wave w owns oc [w*64, +64):
//   wave 0 -> Q, wave 1 -> K, waves 2,3 -> V.
__global__ __launch_bounds__(256) void qkv_proj_kernel(const float* __restrict__ x,
                                                       const _Float16* __restrict__ w16,
                                                       _Float16* __restrict__ Qh,
                                                       _Float16* __restrict__ Kh,
                                                       _Float16* __restrict__ Vt) {
    __shared__ _Float16 xs[16 * 136];   // 16 rows, stride 136 halves (pad 128->136)
    const int t = threadIdx.x;
    const int blk = blockIdx.x;
    const float* xb = x + (size_t)blk * 16 * 128;

    for (int it = 0; it < 2; ++it) {
        int i = t + it * 256;           // 0..511 float4
        int row = i >> 5, c4 = i & 31;
        float4v f = ((const float4v*)xb)[i];
        half4v h;
        h[0] = (_Float16)f[0]; h[1] = (_Float16)f[1];
        h[2] = (_Float16)f[2]; h[3] = (_Float16)f[3];
        *(half4v*)&xs[row * 136 + c4 * 4] = h;
    }
    __syncthreads();

    const int w = t >> 6, lane = t & 63, quad = lane >> 4, n16 = lane & 15;

    half8 a[4];
    for (int c = 0; c < 4; ++c)
        a[c] = *(const half8*)&xs[n16 * 136 + c * 32 + quad * 8];

    float4v acc[4];
    for (int nb = 0; nb < 4; ++nb) acc[nb] = (float4v){0.f, 0.f, 0.f, 0.f};

    for (int c = 0; c < 4; ++c) {
        for (int nb = 0; nb < 4; ++nb) {
            int oc = w * 64 + nb * 16 + n16;
            half8 bfr = *(const half8*)&w16[(size_t)oc * 128 + c * 32 + quad * 8];
            acc[nb] = __builtin_amdgcn_mfma_f32_16x16x32_f16(a[c], bfr, acc[nb], 0, 0, 0);
        }
    }

    const int token0 = blk * 16 + quad * 4;
    if (w == 0) {
        for (int nb = 0; nb < 4; ++nb)
            for (int r = 0; r < 4; ++r)
                Qh[(size_t)(token0 + r) * 64 + nb * 16 + n16] = (_Float16)acc[nb][r];
    } else if (w == 1) {
        for (int nb = 0; nb < 4; ++nb)
            for (int r = 0; r < 4; ++r)
                Kh[(size_t)(token0 + r) * 64 + nb * 16 + n16] = (_Float16)acc[nb][r];
    } else {
        int bb = token0 >> 12, s0 = token0 & 4095;
        for (int nb = 0; nb < 4; ++nb) {
            int vc = (w - 2) * 64 + nb * 16 + n16;
            half4v h;
            h[0] = (_Float16)acc[nb][0]; h[1] = (_Float16)acc[nb][1];
            h[2] = (_Float16)acc[nb][2]; h[3] = (_Float16)acc[nb][3];
            *(half4v*)&Vt[((size_t)bb * 128 + vc) * S_LEN + s0] = h;
        }
    }
}

// ---------------- kernel 2: flash attention, K-split x4, 2 q-tiles/wave -------
// grid (S/128, NCHUNK, B), 256 threads. Wave w owns q rows:
//   set A: qt*128 + w*16 + [0,16)      set B: qt*128 + 64 + w*16 + [0,16)
// Both sets share the staged K/V tile: bK/bV fragments are loaded once and feed
// A and B MFMAs (halves LDS-read instrs per MFMA); softmax of one set overlaps
// MFMA issue of the other (separate VALU/MFMA pipes, register-only deps).
// Shifted-exp softmax: p = exp(s*0.125 - 4) -- constant shift makes partial
// (O, l) EXACTLY additive across key chunks -> accumulate via HW fp32 atomics.
#define KT 64
__global__ __launch_bounds__(256) void flash_kernel(const _Float16* __restrict__ Qh,
                                                    const _Float16* __restrict__ Kh,
                                                    const _Float16* __restrict__ Vt,
                                                    float* __restrict__ out,
                                                    float* __restrict__ lbuf) {
    __shared__ _Float16 Ks[KT * 72];        // K tile [64][64], padded stride 72
    __shared__ _Float16 Vs[128 * 72];       // V^T tile [128][64], padded stride 72
    __shared__ _Float16 PsA[4][16 * 72];    // per-wave P, set A (col-group swizzled)
    __shared__ _Float16 PsB[4][16 * 72];    // per-wave P, set B

    const int t = threadIdx.x;
    const int qt = blockIdx.x, chunk = blockIdx.y, b = blockIdx.z;
    const int w = t >> 6, lane = t & 63, quad = lane >> 4, n16 = lane & 15;

    const size_t qrowA = (size_t)b * S_LEN + qt * 128 + w * 16 + n16;
    const size_t qrowB = qrowA + 64;
    half8 aQ0A = *(const half8*)&Qh[qrowA * 64 + quad * 8];
    half8 aQ1A = *(const half8*)&Qh[qrowA * 64 + 32 + quad * 8];
    half8 aQ0B = *(const half8*)&Qh[qrowB * 64 + quad * 8];
    half8 aQ1B = *(const half8*)&Qh[qrowB * 64 + 32 + quad * 8];

    float4v OA[8], OB[8];
    for (int vb = 0; vb < 8; ++vb) {
        OA[vb] = (float4v){0.f, 0.f, 0.f, 0.f};
        OB[vb] = (float4v){0.f, 0.f, 0.f, 0.f};
    }
    float lsumA[4] = {0.f, 0.f, 0.f, 0.f};
    float lsumB[4] = {0.f, 0.f, 0.f, 0.f};

    const _Float16* Kb = Kh + (size_t)b * S_LEN * 64;
    const _Float16* Vb = Vt + (size_t)b * 128 * S_LEN;

    const int kt0 = chunk * (S_LEN / KT / NCHUNK);
    const int kt1 = kt0 + (S_LEN / KT / NCHUNK);

    const int kr0 = t >> 3, kc0 = t & 7;
    const int kr1 = (t + 256) >> 3;

    // -------- prologue: load tile kt0 into registers --------
    half8 kreg0, kreg1, vreg[4];
    {
        const half8* srcK = (const half8*)(Kb + (size_t)kt0 * KT * 64);
        kreg0 = srcK[t];
        kreg1 = srcK[t + 256];
        for (int it = 0; it < 4; ++it) {
            int i = t + it * 256, row = i >> 3, c8 = i & 7;
            vreg[it] = *(const half8*)&Vb[(size_t)row * S_LEN + kt0 * KT + c8 * 8];
        }
    }

    for (int kt = kt0; kt < kt1; ++kt) {
        __syncthreads();                          // all waves done reading prev tile
        *(half8*)&Ks[kr0 * 72 + kc0 * 8] = kreg0;
        *(half8*)&Ks[kr1 * 72 + kc0 * 8] = kreg1;
        for (int it = 0; it < 4; ++it) {
            int i = t + it * 256, row = i >> 3, c8 = i & 7;
            *(half8*)&Vs[row * 72 + c8 * 8] = vreg[it];
        }
        __syncthreads();                          // tile visible to all waves

        // issue next-tile loads; latency hides under the 48-MFMA compute body
        if (kt + 1 < kt1) {
            const half8* srcK = (const half8*)(Kb + (size_t)(kt + 1) * KT * 64);
            kreg0 = srcK[t];
            kreg1 = srcK[t + 256];
            for (int it = 0; it < 4; ++it) {
                int i = t + it * 256, row = i >> 3, c8 = i & 7;
                vreg[it] = *(const half8*)&Vb[(size_t)row * S_LEN + (kt + 1) * KT + c8 * 8];
            }
        }

        __builtin_amdgcn_s_setprio(1);
        for (int nb = 0; nb < 4; ++nb) {
            half8 bK0 = *(const half8*)&Ks[(nb * 16 + n16) * 72 + quad * 8];
            half8 bK1 = *(const half8*)&Ks[(nb * 16 + n16) * 72 + 32 + quad * 8];
            float4v scA = (float4v){0.f, 0.f, 0.f, 0.f};
            float4v scB = (float4v){0.f, 0.f, 0.f, 0.f};
            scA = __builtin_amdgcn_mfma_f32_16x16x32_f16(aQ0A, bK0, scA, 0, 0, 0);
            scA = __builtin_amdgcn_mfma_f32_16x16x32_f16(aQ1A, bK1, scA, 0, 0, 0);
            scB = __builtin_amdgcn_mfma_f32_16x16x32_f16(aQ0B, bK0, scB, 0, 0, 0);
            scB = __builtin_amdgcn_mfma_f32_16x16x32_f16(aQ1B, bK1, scB, 0, 0, 0);
            for (int r = 0; r < 4; ++r) {
                // exp(s*0.125 - 4) == exp2(fma(s, 0.125*log2e, -4*log2e))
                float pA = __builtin_amdgcn_exp2f(__builtin_fmaf(scA[r], 0.18033688f, -5.7707802f));
                lsumA[r] += pA;
                PsA[w][(quad * 4 + r) * 72 + ((nb ^ quad) << 4) + n16] = (_Float16)pA;
                float pB = __builtin_amdgcn_exp2f(__builtin_fmaf(scB[r], 0.18033688f, -5.7707802f));
                lsumB[r] += pB;
                PsB[w][(quad * 4 + r) * 72 + ((nb ^ quad) << 4) + n16] = (_Float16)pB;
            }
        }
        __builtin_amdgcn_s_setprio(0);

        // per-wave Ps: in-wave DS ordering suffices, no barrier needed.
        const int g0 = ((((quad >> 1) ^ (n16 >> 2)) << 4) | ((quad & 1) * 8));
        const int g1 = (((((quad >> 1) | 2) ^ (n16 >> 2)) << 4) | ((quad & 1) * 8));
        half8 aP0A = *(const half8*)&PsA[w][n16 * 72 + g0];
        half8 aP1A = *(const half8*)&PsA[w][n16 * 72 + g1];
        half8 aP0B = *(const half8*)&PsB[w][n16 * 72 + g0];
        half8 aP1B = *(const half8*)&PsB[w][n16 * 72 + g1];

        __builtin_amdgcn_s_setprio(1);
        for (int vb = 0; vb < 8; ++vb) {
            half8 bV0 = *(const half8*)&Vs[(vb * 16 + n16) * 72 + quad * 8];
            half8 bV1 = *(const half8*)&Vs[(vb * 16 + n16) * 72 + 32 + quad * 8];
            OA[vb] = __builtin_amdgcn_mfma_f32_16x16x32_f16(aP0A, bV0, OA[vb], 0, 0, 0);
            OA[vb] = __builtin_amdgcn_mfma_f32_16x16x32_f16(aP1A, bV1, OA[vb], 0, 0, 0);
            OB[vb] = __builtin_amdgcn_mfma_f32_16x16x32_f16(aP0B, bV0, OB[vb], 0, 0, 0);
            OB[vb] = __builtin_amdgcn_mfma_f32_16x16x32_f16(aP1B, bV1, OB[vb], 0, 0, 0);
        }
        __builtin_amdgcn_s_setprio(0);
    }

    // reduce row sums across the 16 lanes of each quad
    for (int m = 1; m < 16; m <<= 1)
        for (int r = 0; r < 4; ++r) {
            lsumA[r] += __shfl_xor(lsumA[r], m, 16);
            lsumB[r] += __shfl_xor(lsumB[r], m, 16);
        }

    const int row0A = qt * 128 + w * 16 + quad * 4;          // within batch
    const int row0B = row0A + 64;
    if (n16 == 0)
        for (int r = 0; r < 4; ++r) {
            unsafeAtomicAdd(&lbuf[b * S_LEN + row0A + r], lsumA[r]);
            unsafeAtomicAdd(&lbuf[b * S_LEN + row0B + r], lsumB[r]);
        }

    float* obA = out + ((size_t)b * S_LEN + row0A) * 128;
    float* obB = out + ((size_t)b * S_LEN + row0B) * 128;
    for (int vb = 0; vb < 8; ++vb)
        for (int r = 0; r < 4; ++r) {
            unsafeAtomicAdd(&obA[(size_t)r * 128 + vb * 16 + n16], OA[vb][r]);
            unsafeAtomicAdd(&obB[(size_t)r * 128 + vb * 16 + n16], OB[vb][r]);
        }
}

// ---------------- kernel 3: normalize out by row sums -------------------------
__global__ __launch_bounds__(256) void norm_kernel(float4v* __restrict__ out4,
                                                   const float* __restrict__ lbuf) {
    int i = blockIdx.x * 256 + threadIdx.x;   // 0..524287 (32 float4 per row)
    float inv = 1.0f / lbuf[i >> 5];
    float4v v = out4[i];
    v[0] *= inv; v[1] *= inv; v[2] *= inv; v[3] *= inv;
    out4[i] = v;
}

// ---------------- launch ------------------------------------------------------
extern "C" void kernel_launch(void* const* d_in, const int* in_sizes, int n_in,
                              void* d_out, int out_size, void* d_ws, size_t ws_size,
                              hipStream_t stream) {
    const float* x  = (const float*)d_in[0];
    const float* Wq = (const float*)d_in[1];
    const float* Wk = (const float*)d_in[2];
    const float* Wv = (const float*)d_in[3];
    float* out = (float*)d_out;

    _Float16* ws = (_Float16*)d_ws;
    _Float16* w16 = ws + WS_W16;
    _Float16* Qh  = ws + WS_QH;
    _Float16* Kh  = ws + WS_KH;
    _Float16* Vt  = ws + WS_VT;
    float*    lbuf = (float*)(ws + WS_L);

    init_kernel<<<2048, 256, 0, stream>>>(Wq, Wk, Wv, w16, (float4v*)out, (float4v*)lbuf);
    qkv_proj_kernel<<<NBATCH * S_LEN / 16, 256, 0, stream>>>(x, w16, Qh, Kh, Vt);
    flash_kernel<<<dim3(S_LEN / 128, NCHUNK, NBATCH), 256, 0, stream>>>(Qh, Kh, Vt, out, lbuf);
    norm_kernel<<<2048, 256, 0, stream>>>((float4v*)out, lbuf);
}

// Round 3
// 131.336 us; speedup vs baseline: 1.1740x; 1.0380x over previous
//
#include <hip/hip_runtime.h>

typedef _Float16 half8 __attribute__((ext_vector_type(8)));
typedef _Float16 half4v __attribute__((ext_vector_type(4)));
typedef float   float4v __attribute__((ext_vector_type(4)));

#define S_LEN 4096
#define NBATCH 4
#define NCHUNK 4          // K-split factor: each chunk covers S/NCHUNK keys
// ws layout in halves:
//   W16  @ 0        : 256*128      = 32768
//   Qh   @ 32768    : 16384*64     = 1048576   (token-major [B*S][64])
//   Kh   @ 1081344  : 16384*64     = 1048576
//   Vt   @ 2129920  : 4*128*4096   = 2097152   (per-batch transposed [128][S])
//   L    @ 4227072  : 16384 floats (row sum-of-exp accumulators)
#define WS_W16 0
#define WS_QH  32768
#define WS_KH  1081344
#define WS_VT  2129920
#define WS_L   4227072

// ---------------- kernel 0: zero accumulators + convert weights (fused) ------
__global__ __launch_bounds__(256) void init_kernel(const float* __restrict__ Wq,
                                                   const float* __restrict__ Wk,
                                                   const float* __restrict__ Wv,
                                                   _Float16* __restrict__ w16,
                                                   float4v* __restrict__ out4,
                                                   float4v* __restrict__ l4) {
    int i = blockIdx.x * 256 + threadIdx.x;   // 0..524287
    out4[i] = (float4v){0.f, 0.f, 0.f, 0.f};
    if (i < 4096) l4[i] = (float4v){0.f, 0.f, 0.f, 0.f};
    if (i < 32768) {
        int row = i >> 7, col = i & 127;
        float v;
        if (row < 64)       v = Wq[row * 128 + col];
        else if (row < 128) v = Wk[(row - 64) * 128 + col];
        else                v = Wv[(row - 128) * 128 + col];
        w16[i] = (_Float16)v;
    }
}

// ---------------- kernel 1: QKV projection via MFMA ---------------------------
// grid 1024 blocks x 256 thr; block owns 16 tokens; wave w owns oc [w*64, +64):
//   wave 0 -> Q, wave 1 -> K, waves 2,3 -> V.
__global__ __launch_bounds__(256) void qkv_proj_kernel(const float* __restrict__ x,
                                                       const _Float16* __restrict__ w16,
                                                       _Float16* __restrict__ Qh,
                                                       _Float16* __restrict__ Kh,
                                                       _Float16* __restrict__ Vt) {
    __shared__ _Float16 xs[16 * 136];   // 16 rows, stride 136 halves (pad 128->136)
    const int t = threadIdx.x;
    const int blk = blockIdx.x;
    const float* xb = x + (size_t)blk * 16 * 128;

    for (int it = 0; it < 2; ++it) {
        int i = t + it * 256;           // 0..511 float4
        int row = i >> 5, c4 = i & 31;
        float4v f = ((const float4v*)xb)[i];
        half4v h;
        h[0] = (_Float16)f[0]; h[1] = (_Float16)f[1];
        h[2] = (_Float16)f[2]; h[3] = (_Float16)f[3];
        *(half4v*)&xs[row * 136 + c4 * 4] = h;
    }
    __syncthreads();

    const int w = t >> 6, lane = t & 63, quad = lane >> 4, n16 = lane & 15;

    half8 a[4];
    for (int c = 0; c < 4; ++c)
        a[c] = *(const half8*)&xs[n16 * 136 + c * 32 + quad * 8];

    float4v acc[4];
    for (int nb = 0; nb < 4; ++nb) acc[nb] = (float4v){0.f, 0.f, 0.f, 0.f};

    for (int c = 0; c < 4; ++c) {
        for (int nb = 0; nb < 4; ++nb) {
            int oc = w * 64 + nb * 16 + n16;
            half8 bfr = *(const half8*)&w16[(size_t)oc * 128 + c * 32 + quad * 8];
            acc[nb] = __builtin_amdgcn_mfma_f32_16x16x32_f16(a[c], bfr, acc[nb], 0, 0, 0);
        }
    }

    const int token0 = blk * 16 + quad * 4;
    if (w == 0) {
        for (int nb = 0; nb < 4; ++nb)
            for (int r = 0; r < 4; ++r)
                Qh[(size_t)(token0 + r) * 64 + nb * 16 + n16] = (_Float16)acc[nb][r];
    } else if (w == 1) {
        for (int nb = 0; nb < 4; ++nb)
            for (int r = 0; r < 4; ++r)
                Kh[(size_t)(token0 + r) * 64 + nb * 16 + n16] = (_Float16)acc[nb][r];
    } else {
        int bb = token0 >> 12, s0 = token0 & 4095;
        for (int nb = 0; nb < 4; ++nb) {
            int vc = (w - 2) * 64 + nb * 16 + n16;
            half4v h;
            h[0] = (_Float16)acc[nb][0]; h[1] = (_Float16)acc[nb][1];
            h[2] = (_Float16)acc[nb][2]; h[3] = (_Float16)acc[nb][3];
            *(half4v*)&Vt[((size_t)bb * 128 + vc) * S_LEN + s0] = h;
        }
    }
}

// ---------------- kernel 2: flash attention, K-split x4, 2 q-tiles/wave -------
// grid (S/128, NCHUNK, B), 256 threads. Wave w owns q rows:
//   set A: qt*128 + w*16 + [0,16)      set B: qt*128 + 64 + w*16 + [0,16)
//
// SWAPPED QK^T: sc = mfma(K_frag, Q_frag) puts q lane-local:
//   lane (quad,n16) holds P[q=n16][k = nb*16 + quad*4 + r]  (r = reg idx)
// P never touches LDS. The PV MFMA uses a permuted K-order (valid since A and
// B agree): A-frag slot (quad,j) = key (j>>2)*16 + quad*4 + (j&3) + 32h, built
// by register packing; the V B-frag reads with the same permutation as two
// ds_read_b64 per half (2-way bank aliasing = free).
//
// Shifted-exp softmax: p = exp(s*0.125 - 4) -- constant shift makes partial
// (O, l) EXACTLY additive across key chunks -> accumulate via HW fp32 atomics.
#define KT 64
__global__ __launch_bounds__(256) void flash_kernel(const _Float16* __restrict__ Qh,
                                                    const _Float16* __restrict__ Kh,
                                                    const _Float16* __restrict__ Vt,
                                                    float* __restrict__ out,
                                                    float* __restrict__ lbuf) {
    __shared__ _Float16 Ks[KT * 72];        // K tile [64][64], padded stride 72
    __shared__ _Float16 Vs[128 * 72];       // V^T tile [128][64], padded stride 72

    const int t = threadIdx.x;
    const int qt = blockIdx.x, chunk = blockIdx.y, b = blockIdx.z;
    const int w = t >> 6, lane = t & 63, quad = lane >> 4, n16 = lane & 15;

    const size_t qrowA = (size_t)b * S_LEN + qt * 128 + w * 16 + n16;
    const size_t qrowB = qrowA + 64;
    half8 aQ0A = *(const half8*)&Qh[qrowA * 64 + quad * 8];
    half8 aQ1A = *(const half8*)&Qh[qrowA * 64 + 32 + quad * 8];
    half8 aQ0B = *(const half8*)&Qh[qrowB * 64 + quad * 8];
    half8 aQ1B = *(const half8*)&Qh[qrowB * 64 + 32 + quad * 8];

    float4v OA[8], OB[8];
    for (int vb = 0; vb < 8; ++vb) {
        OA[vb] = (float4v){0.f, 0.f, 0.f, 0.f};
        OB[vb] = (float4v){0.f, 0.f, 0.f, 0.f};
    }
    float lsumA = 0.f, lsumB = 0.f;

    const _Float16* Kb = Kh + (size_t)b * S_LEN * 64;
    const _Float16* Vb = Vt + (size_t)b * 128 * S_LEN;

    const int kt0 = chunk * (S_LEN / KT / NCHUNK);
    const int kt1 = kt0 + (S_LEN / KT / NCHUNK);

    const int kr0 = t >> 3, kc0 = t & 7;
    const int kr1 = (t + 256) >> 3;

    // -------- prologue: load tile kt0 into registers --------
    half8 kreg0, kreg1, vreg[4];
    {
        const half8* srcK = (const half8*)(Kb + (size_t)kt0 * KT * 64);
        kreg0 = srcK[t];
        kreg1 = srcK[t + 256];
        for (int it = 0; it < 4; ++it) {
            int i = t + it * 256, row = i >> 3, c8 = i & 7;
            vreg[it] = *(const half8*)&Vb[(size_t)row * S_LEN + kt0 * KT + c8 * 8];
        }
    }

    for (int kt = kt0; kt < kt1; ++kt) {
        __syncthreads();                          // all waves done reading prev tile
        *(half8*)&Ks[kr0 * 72 + kc0 * 8] = kreg0;
        *(half8*)&Ks[kr1 * 72 + kc0 * 8] = kreg1;
        for (int it = 0; it < 4; ++it) {
            int i = t + it * 256, row = i >> 3, c8 = i & 7;
            *(half8*)&Vs[row * 72 + c8 * 8] = vreg[it];
        }
        __syncthreads();                          // tile visible to all waves

        // issue next-tile loads; latency hides under the 48-MFMA compute body
        if (kt + 1 < kt1) {
            const half8* srcK = (const half8*)(Kb + (size_t)(kt + 1) * KT * 64);
            kreg0 = srcK[t];
            kreg1 = srcK[t + 256];
            for (int it = 0; it < 4; ++it) {
                int i = t + it * 256, row = i >> 3, c8 = i & 7;
                vreg[it] = *(const half8*)&Vb[(size_t)row * S_LEN + (kt + 1) * KT + c8 * 8];
            }
        }

        // -------- QK^T (swapped) + softmax; P packed into A-fragments --------
        half8 aP0A, aP1A, aP0B, aP1B;   // element 4*(nb&1)+r of half h <- p[nb=2h+(nb&1)][r]
        __builtin_amdgcn_s_setprio(1);
#pragma unroll
        for (int nb = 0; nb < 4; ++nb) {
            half8 bK0 = *(const half8*)&Ks[(nb * 16 + n16) * 72 + quad * 8];
            half8 bK1 = *(const half8*)&Ks[(nb * 16 + n16) * 72 + 32 + quad * 8];
            float4v scA = (float4v){0.f, 0.f, 0.f, 0.f};
            float4v scB = (float4v){0.f, 0.f, 0.f, 0.f};
            scA = __builtin_amdgcn_mfma_f32_16x16x32_f16(bK0, aQ0A, scA, 0, 0, 0);
            scA = __builtin_amdgcn_mfma_f32_16x16x32_f16(bK1, aQ1A, scA, 0, 0, 0);
            scB = __builtin_amdgcn_mfma_f32_16x16x32_f16(bK0, aQ0B, scB, 0, 0, 0);
            scB = __builtin_amdgcn_mfma_f32_16x16x32_f16(bK1, aQ1B, scB, 0, 0, 0);
#pragma unroll
            for (int r = 0; r < 4; ++r) {
                // exp(s*0.125 - 4) == exp2(fma(s, 0.125*log2e, -4*log2e))
                float pa = __builtin_amdgcn_exp2f(__builtin_fmaf(scA[r], 0.18033688f, -5.7707802f));
                lsumA += pa;
                float pb = __builtin_amdgcn_exp2f(__builtin_fmaf(scB[r], 0.18033688f, -5.7707802f));
                lsumB += pb;
                int slot = (nb & 1) * 4 + r;
                if (nb < 2) { aP0A[slot] = (_Float16)pa; aP0B[slot] = (_Float16)pb; }
                else        { aP1A[slot] = (_Float16)pa; aP1B[slot] = (_Float16)pb; }
            }
        }
        __builtin_amdgcn_s_setprio(0);

        // -------- PV with permuted K-order (register A-frag, b64 V reads) -----
        __builtin_amdgcn_s_setprio(1);
#pragma unroll
        for (int vb = 0; vb < 8; ++vb) {
            const _Float16* vrow = &Vs[(vb * 16 + n16) * 72];
            half4v v00 = *(const half4v*)&vrow[quad * 4];          // keys quad*4+r
            half4v v01 = *(const half4v*)&vrow[16 + quad * 4];     // keys 16+quad*4+r
            half4v v10 = *(const half4v*)&vrow[32 + quad * 4];     // keys 32+quad*4+r
            half4v v11 = *(const half4v*)&vrow[48 + quad * 4];     // keys 48+quad*4+r
            half8 bV0, bV1;
#pragma unroll
            for (int j = 0; j < 4; ++j) {
                bV0[j] = v00[j]; bV0[4 + j] = v01[j];
                bV1[j] = v10[j]; bV1[4 + j] = v11[j];
            }
            OA[vb] = __builtin_amdgcn_mfma_f32_16x16x32_f16(aP0A, bV0, OA[vb], 0, 0, 0);
            OA[vb] = __builtin_amdgcn_mfma_f32_16x16x32_f16(aP1A, bV1, OA[vb], 0, 0, 0);
            OB[vb] = __builtin_amdgcn_mfma_f32_16x16x32_f16(aP0B, bV0, OB[vb], 0, 0, 0);
            OB[vb] = __builtin_amdgcn_mfma_f32_16x16x32_f16(aP1B, bV1, OB[vb], 0, 0, 0);
        }
        __builtin_amdgcn_s_setprio(0);
    }

    // each lane holds the partial row-sum for q = n16; reduce across quads
    lsumA += __shfl_xor(lsumA, 16);
    lsumA += __shfl_xor(lsumA, 32);
    lsumB += __shfl_xor(lsumB, 16);
    lsumB += __shfl_xor(lsumB, 32);

    const int rowbaseA = qt * 128 + w * 16;                 // within batch
    const int rowbaseB = rowbaseA + 64;
    if (quad == 0) {
        unsafeAtomicAdd(&lbuf[b * S_LEN + rowbaseA + n16], lsumA);
        unsafeAtomicAdd(&lbuf[b * S_LEN + rowbaseB + n16], lsumB);
    }

    const int row0A = rowbaseA + quad * 4;
    const int row0B = rowbaseB + quad * 4;
    float* obA = out + ((size_t)b * S_LEN + row0A) * 128;
    float* obB = out + ((size_t)b * S_LEN + row0B) * 128;
    for (int vb = 0; vb < 8; ++vb)
        for (int r = 0; r < 4; ++r) {
            unsafeAtomicAdd(&obA[(size_t)r * 128 + vb * 16 + n16], OA[vb][r]);
            unsafeAtomicAdd(&obB[(size_t)r * 128 + vb * 16 + n16], OB[vb][r]);
        }
}

// ---------------- kernel 3: normalize out by row sums -------------------------
__global__ __launch_bounds__(256) void norm_kernel(float4v* __restrict__ out4,
                                                   const float* __restrict__ lbuf) {
    int i = blockIdx.x * 256 + threadIdx.x;   // 0..524287 (32 float4 per row)
    float inv = 1.0f / lbuf[i >> 5];
    float4v v = out4[i];
    v[0] *= inv; v[1] *= inv; v[2] *= inv; v[3] *= inv;
    out4[i] = v;
}

// ---------------- launch ------------------------------------------------------
extern "C" void kernel_launch(void* const* d_in, const int* in_sizes, int n_in,
                              void* d_out, int out_size, void* d_ws, size_t ws_size,
                              hipStream_t stream) {
    const float* x  = (const float*)d_in[0];
    const float* Wq = (const float*)d_in[1];
    const float* Wk = (const float*)d_in[2];
    const float* Wv = (const float*)d_in[3];
    float* out = (float*)d_out;

    _Float16* ws = (_Float16*)d_ws;
    _Float16* w16 = ws + WS_W16;
    _Float16* Qh  = ws + WS_QH;
    _Float16* Kh  = ws + WS_KH;
    _Float16* Vt  = ws + WS_VT;
    float*    lbuf = (float*)(ws + WS_L);

    init_kernel<<<2048, 256, 0, stream>>>(Wq, Wk, Wv, w16, (float4v*)out, (float4v*)lbuf);
    qkv_proj_kernel<<<NBATCH * S_LEN / 16, 256, 0, stream>>>(x, w16, Qh, Kh, Vt);
    flash_kernel<<<dim3(S_LEN / 128, NCHUNK, NBATCH), 256, 0, stream>>>(Qh, Kh, Vt, out, lbuf);
    norm_kernel<<<2048, 256, 0, stream>>>((float4v*)out, lbuf);
}